// Round 17
// baseline (85.946 us; speedup 1.0000x reference)
//
#include <hip/hip_runtime.h>

// out = atoms_x - segment_mean(atoms_x, graph_batch)[graph_batch], gb SORTED.
// TWO MINIMAL STREAM PASSES (decomposition + roofline probe):
//  K1 (sum pass, r15 machinery): chunked loads -> per-lane run accum ->
//     per-wave LDS slot table (+hoisted halo completion). OWNER-WRITE rule:
//     the wave holding a molecule's FIRST atom writes its completed mean to
//     ws[mol] with a plain float4 store (halos make every sum complete) ->
//     no global atomics, no memset. Writes only ~3.2 MB.
//  K2 (subtract pass): pure stream out[i] = x[i] - ws[gb[i]].xyz. No LDS,
//     no halos, no atomics -> copy-class kernel.

static constexpr int WAVE   = 64;
static constexpr int WPB    = 4;                 // independent waves / WG
static constexpr int TPB    = WAVE * WPB;
static constexpr int CPT    = 8;                 // atoms per lane (K1)
static constexpr int WCHUNK = WAVE * CPT;        // 512 atoms per wave
static constexpr int SLOTS  = 64;                // id-span per chunk (exp ~13)

#define LDS_FENCE() asm volatile("s_waitcnt lgkmcnt(0)" ::: "memory")

__device__ void k1_serial_fallback(const float* __restrict__ x,
                                   const int* __restrict__ gb,
                                   float* __restrict__ ws, int n,
                                   long long cs, long long ce, int lane) {
  // Pathological id-sparsity; wave-uniform, never hot, correct.
  if (lane != 0) return;
  long long i = cs;
  while (i < ce) {
    int id = gb[i];
    long long rs = i; while (rs > 0 && gb[rs - 1] == id) --rs;
    long long re = i; while (re < n && gb[re] == id) ++re;
    if (rs >= cs) {  // run starts in this chunk -> we own its mean
      float sx = 0.f, sy = 0.f, sz = 0.f;
      for (long long k = rs; k < re; ++k) {
        sx += x[k * 3 + 0]; sy += x[k * 3 + 1]; sz += x[k * 3 + 2];
      }
      float inv = 1.f / (float)(re - rs);
      *reinterpret_cast<float4*>(&ws[(size_t)id * 4]) =
          make_float4(sx * inv, sy * inv, sz * inv, (float)(re - rs));
    }
    i = re;
  }
}

__global__ __launch_bounds__(TPB) void k1_means(
    const float* __restrict__ x, const int* __restrict__ gb,
    float* __restrict__ ws, int n) {
  __shared__ float sums_all[WPB][SLOTS * 4];  // 1 KB / wave

  const int w = threadIdx.x >> 6;
  const int lane = threadIdx.x & 63;
  float* sums = sums_all[w];

  const long long cs = ((long long)blockIdx.x * WPB + w) * WCHUNK;
  if (cs >= (long long)n) return;  // idle wave; no barriers anywhere
  const long long ce = (cs + WCHUNK < (long long)n) ? cs + WCHUNK : (long long)n;

  if (ce - cs < WCHUNK) {
    // ---- partial tail chunk (at most one wave in the grid) ----
    const int fid = gb[cs];
    const int lid = gb[ce - 1];
    const int span = lid - fid + 1;
    if (span > SLOTS) { k1_serial_fallback(x, gb, ws, n, cs, ce, lane); return; }
    for (int s = lane; s < span * 4; s += WAVE) sums[s] = 0.f;
    LDS_FENCE();
    for (long long i = cs + lane; i < ce; i += WAVE) {
      int s = (gb[i] - fid) * 4;
      atomicAdd(&sums[s + 0], x[i * 3 + 0]);
      atomicAdd(&sums[s + 1], x[i * 3 + 1]);
      atomicAdd(&sums[s + 2], x[i * 3 + 2]);
      atomicAdd(&sums[s + 3], 1.f);
    }
    if (cs > 0) {  // front halo only (ce == n here)
      float hx = 0.f, hy = 0.f, hz = 0.f, hc = 0.f;
      long long off = 1 + lane;
      for (;;) {
        long long i = cs - off;
        bool m = (i >= 0) && (gb[i] == fid);
        if (m) { hx += x[i*3+0]; hy += x[i*3+1]; hz += x[i*3+2]; hc += 1.f; }
        if (__popcll(__ballot(m)) < WAVE) break;
        off += WAVE;
      }
#pragma unroll
      for (int d = 1; d < 64; d <<= 1) {
        hx += __shfl_xor(hx, d); hy += __shfl_xor(hy, d);
        hz += __shfl_xor(hz, d); hc += __shfl_xor(hc, d);
      }
      if (lane == 0 && hc > 0.f) {
        atomicAdd(&sums[0], hx); atomicAdd(&sums[1], hy);
        atomicAdd(&sums[2], hz); atomicAdd(&sums[3], hc);
      }
    }
    LDS_FENCE();
    int s0 = 0;
    if (cs > 0 && gb[cs - 1] == fid) s0 = 1;  // fid owned by earlier chunk
    for (int s = s0 + lane; s < span; s += WAVE) {
      float c = sums[s * 4 + 3];
      float inv = (c > 0.f) ? 1.f / c : 0.f;
      *reinterpret_cast<float4*>(&ws[(size_t)(fid + s) * 4]) =
          make_float4(sums[s*4+0] * inv, sums[s*4+1] * inv,
                      sums[s*4+2] * inv, c);
    }
    return;
  }

  const long long base = cs + (long long)lane * CPT;

  // ---- main load burst (chunked float4/int4) ----
  float f[CPT * 3];
  int ids[CPT];
  {
    const float4* xv = reinterpret_cast<const float4*>(x + base * 3);
#pragma unroll
    for (int j = 0; j < CPT * 3 / 4; ++j) {
      float4 v = xv[j];
      f[j * 4 + 0] = v.x; f[j * 4 + 1] = v.y;
      f[j * 4 + 2] = v.z; f[j * 4 + 3] = v.w;
    }
    const int4* gv = reinterpret_cast<const int4*>(gb + base);
#pragma unroll
    for (int j = 0; j < CPT / 4; ++j) {
      int4 g = gv[j];
      ids[j * 4 + 0] = g.x; ids[j * 4 + 1] = g.y;
      ids[j * 4 + 2] = g.z; ids[j * 4 + 3] = g.w;
    }
  }

  // ---- HOISTED halo probes (issued with the main burst) ----
  const bool hasF = (cs > 0);
  const bool hasB = (ce < (long long)n);
  int pf = -1, pb = -1;
  if (hasF) pf = gb[cs - 1 - lane];
  if (hasB && ce + lane < (long long)n) pb = gb[ce + lane];

  reinterpret_cast<float4*>(sums)[lane] = make_float4(0.f, 0.f, 0.f, 0.f);
  LDS_FENCE();

  const int fid = __shfl(ids[0], 0);
  const int lid = __shfl(ids[CPT - 1], WAVE - 1);
  const int span = lid - fid + 1;
  if (span > SLOTS) { k1_serial_fallback(x, gb, ws, n, cs, ce, lane); return; }

  // ---- masked x-halo loads BEFORE the accumulate (latency hidden) ----
  const bool mf = hasF && (pf == fid);
  const bool mb = hasB && (pb == lid);
  float fhx = 0.f, fhy = 0.f, fhz = 0.f, fhc = 0.f;
  if (mf) {
    long long i = cs - 1 - lane;
    fhx = x[i * 3 + 0]; fhy = x[i * 3 + 1]; fhz = x[i * 3 + 2]; fhc = 1.f;
  }
  float bhx = 0.f, bhy = 0.f, bhz = 0.f, bhc = 0.f;
  if (mb) {
    long long i = ce + lane;
    bhx = x[i * 3 + 0]; bhy = x[i * 3 + 1]; bhz = x[i * 3 + 2]; bhc = 1.f;
  }

  // ---- per-lane run accumulation, flush at id boundaries ----
  {
    int cur = ids[0];
    float sx = 0.f, sy = 0.f, sz = 0.f, sc = 0.f;
#pragma unroll
    for (int j = 0; j < CPT; ++j) {
      if (ids[j] != cur) {
        int s = (cur - fid) * 4;
        atomicAdd(&sums[s + 0], sx); atomicAdd(&sums[s + 1], sy);
        atomicAdd(&sums[s + 2], sz); atomicAdd(&sums[s + 3], sc);
        cur = ids[j]; sx = sy = sz = sc = 0.f;
      }
      sx += f[j * 3 + 0]; sy += f[j * 3 + 1]; sz += f[j * 3 + 2]; sc += 1.f;
    }
    int s = (cur - fid) * 4;
    atomicAdd(&sums[s + 0], sx); atomicAdd(&sums[s + 1], sy);
    atomicAdd(&sums[s + 2], sz); atomicAdd(&sums[s + 3], sc);
  }

  // ---- front halo: continuation (rare: run >= 64) + reduce + flush ----
  if (hasF) {
    unsigned long long bal = __ballot(mf);
    long long off = (long long)WAVE + 1 + lane;
    while (__popcll(bal) == WAVE) {
      long long i = cs - off;
      bool m2 = (i >= 0) && (gb[i] == fid);
      if (m2) {
        fhx += x[i*3+0]; fhy += x[i*3+1]; fhz += x[i*3+2]; fhc += 1.f;
      }
      bal = __ballot(m2);
      off += WAVE;
    }
#pragma unroll
    for (int d = 1; d < 64; d <<= 1) {
      fhx += __shfl_xor(fhx, d); fhy += __shfl_xor(fhy, d);
      fhz += __shfl_xor(fhz, d); fhc += __shfl_xor(fhc, d);
    }
    if (lane == 0 && fhc > 0.f) {
      atomicAdd(&sums[0], fhx); atomicAdd(&sums[1], fhy);
      atomicAdd(&sums[2], fhz); atomicAdd(&sums[3], fhc);
    }
  }
  // ---- back halo ----
  if (hasB) {
    unsigned long long bal = __ballot(mb);
    long long off = (long long)WAVE + lane;
    while (__popcll(bal) == WAVE) {
      long long i = ce + off;
      bool m2 = (i < (long long)n) && (gb[i] == lid);
      if (m2) {
        bhx += x[i*3+0]; bhy += x[i*3+1]; bhz += x[i*3+2]; bhc += 1.f;
      }
      bal = __ballot(m2);
      off += WAVE;
    }
#pragma unroll
    for (int d = 1; d < 64; d <<= 1) {
      bhx += __shfl_xor(bhx, d); bhy += __shfl_xor(bhy, d);
      bhz += __shfl_xor(bhz, d); bhc += __shfl_xor(bhc, d);
    }
    if (lane == 0 && bhc > 0.f) {
      int s = (lid - fid) * 4;
      atomicAdd(&sums[s + 0], bhx); atomicAdd(&sums[s + 1], bhy);
      atomicAdd(&sums[s + 2], bhz); atomicAdd(&sums[s + 3], bhc);
    }
  }
  LDS_FENCE();

  // ---- owner-write completed means to ws (plain stores, no atomics) ----
  int s0 = (hasF && __shfl((int)mf, 0)) ? 1 : 0;  // fid owned by earlier chunk?
  for (int s = s0 + lane; s < span; s += WAVE) {
    float c = sums[s * 4 + 3];
    float inv = (c > 0.f) ? 1.f / c : 0.f;
    *reinterpret_cast<float4*>(&ws[(size_t)(fid + s) * 4]) =
        make_float4(sums[s*4+0] * inv, sums[s*4+1] * inv,
                    sums[s*4+2] * inv, c);
  }
}

// ---- K2: pure stream subtract ----
__global__ __launch_bounds__(256) void k2_subtract(
    const float* __restrict__ x, const int* __restrict__ gb,
    const float* __restrict__ ws, float* __restrict__ out, int n) {
  long long t = (long long)blockIdx.x * blockDim.x + threadIdx.x;
  long long base = t * 4;
  if (base >= n) return;

  if (base + 4 <= n) {
    int4 g = *reinterpret_cast<const int4*>(gb + base);
    const float4* xv = reinterpret_cast<const float4*>(x + base * 3);
    float4 v0 = xv[0], v1 = xv[1], v2 = xv[2];
    float4 m0 = *reinterpret_cast<const float4*>(ws + (size_t)g.x * 4);
    float4 m1 = *reinterpret_cast<const float4*>(ws + (size_t)g.y * 4);
    float4 m2 = *reinterpret_cast<const float4*>(ws + (size_t)g.z * 4);
    float4 m3 = *reinterpret_cast<const float4*>(ws + (size_t)g.w * 4);
    float4 o0, o1, o2;
    o0.x = v0.x - m0.x; o0.y = v0.y - m0.y; o0.z = v0.z - m0.z;
    o0.w = v0.w - m1.x;
    o1.x = v1.x - m1.y; o1.y = v1.y - m1.z;
    o1.z = v1.z - m2.x; o1.w = v1.w - m2.y;
    o2.x = v2.x - m2.z;
    o2.y = v2.y - m3.x; o2.z = v2.z - m3.y; o2.w = v2.w - m3.z;
    float4* ov = reinterpret_cast<float4*>(out + base * 3);
    ov[0] = o0; ov[1] = o1; ov[2] = o2;
  } else {
    for (long long i = base; i < n; ++i) {
      int id = gb[i];
      out[i * 3 + 0] = x[i * 3 + 0] - ws[(size_t)id * 4 + 0];
      out[i * 3 + 1] = x[i * 3 + 1] - ws[(size_t)id * 4 + 1];
      out[i * 3 + 2] = x[i * 3 + 2] - ws[(size_t)id * 4 + 2];
    }
  }
}

extern "C" void kernel_launch(void* const* d_in, const int* in_sizes, int n_in,
                              void* d_out, int out_size, void* d_ws, size_t ws_size,
                              hipStream_t stream) {
  const float* x = (const float*)d_in[0];
  const int* gb = (const int*)d_in[1];
  float* out = (float*)d_out;
  float* ws = (float*)d_ws;  // [num_mols][4] = {mx, my, mz, cnt}, owner-written
  const int n = in_sizes[0] / 3;  // atoms

  long long nchunks = ((long long)n + WCHUNK - 1) / WCHUNK;
  int blocks1 = (int)((nchunks + WPB - 1) / WPB);
  k1_means<<<blocks1, TPB, 0, stream>>>(x, gb, ws, n);

  long long threads2 = ((long long)n + 3) / 4;
  int blocks2 = (int)((threads2 + 255) / 256);
  k2_subtract<<<blocks2, 256, 0, stream>>>(x, gb, ws, out, n);
}